// Round 6
// baseline (1093.108 us; speedup 1.0000x reference)
//
#include <hip/hip_runtime.h>
#include <cstddef>

// Problem constants: B=64, C=256, H*W=1024, N=B*HW=65536, n_embed=1024.
static constexpr int OUT_DIFF = 16777216;   // diff region (also used as "flat" staging)
static constexpr int OUT_IDX  = 33554432;
static constexpr int OUT_ENEW = 33619968;
static constexpr int OUT_CSN  = 33882112;
static constexpr int OUT_EAVG = 33883136;

__device__ __forceinline__ void gll16(const float* g, float* l) {
  __builtin_amdgcn_global_load_lds((const __attribute__((address_space(1))) void*)g,
                                   (__attribute__((address_space(3))) void*)l, 16, 0, 0);
}

// ---------------------------------------------------------------- K1: prep
// blocks 0..63 : embedT[k][c] = embed[c][k] via 64x64 LDS tile (coalesced both sides)
// blocks 64..67: esq[k] = sum_c embed[c][k]^2, one code per thread, coalesced
//               loads, sequential ascending-c square-then-add (bitwise as before)
// block 68     : zero the histogram counters
__global__ __launch_bounds__(256) void k_prep(const float* __restrict__ embed,
                                              float* __restrict__ embedT,
                                              float* __restrict__ esq,
                                              int* __restrict__ cnt) {
  const int wg = blockIdx.x;
  const int tid = threadIdx.x;
  if (wg < 64) {
    __shared__ float tt[64 * 65];
    const int k0 = (wg >> 2) * 64, c0 = (wg & 3) * 64;
#pragma unroll
    for (int r = 0; r < 4; ++r) {
      int i = tid + r * 256;
      int cc = i >> 4, kL = (i & 15) * 4;
      float4 v = *(const float4*)(embed + (size_t)(c0 + cc) * 1024 + k0 + kL);
      tt[(kL + 0) * 65 + cc] = v.x;
      tt[(kL + 1) * 65 + cc] = v.y;
      tt[(kL + 2) * 65 + cc] = v.z;
      tt[(kL + 3) * 65 + cc] = v.w;
    }
    __syncthreads();
#pragma unroll
    for (int r = 0; r < 4; ++r) {
      int i = tid + r * 256;
      int kk = i >> 4, cL = (i & 15) * 4;
      float4 o;
      o.x = tt[kk * 65 + cL + 0];
      o.y = tt[kk * 65 + cL + 1];
      o.z = tt[kk * 65 + cL + 2];
      o.w = tt[kk * 65 + cL + 3];
      *(float4*)(embedT + (size_t)(k0 + kk) * 256 + c0 + cL) = o;
    }
  } else if (wg < 68) {
    const int k = (wg - 64) * 256 + tid;
    {
#pragma clang fp contract(off)
      float s = 0.f;
#pragma unroll 1
      for (int c = 0; c < 256; ++c) { float u = embed[(size_t)c * 1024 + k]; s += u * u; }
      esq[k] = s;
    }
  } else {
    ((int4*)cnt)[tid] = make_int4(0, 0, 0, 0);
  }
}

// ------------------------------------------------------------- K2: flatten
// input (B,C,HW) -> flat (N,C) via LDS tile; flat staged in the diff region.
__global__ __launch_bounds__(256) void k_flatten(const float* __restrict__ inp,
                                                 float* __restrict__ flat) {
  const int tid = threadIdx.x;
  const int b = blockIdx.x >> 4;
  const int hw0 = (blockIdx.x & 15) * 64;
  __shared__ float t[64 * 257];
#pragma unroll
  for (int r = 0; r < 16; ++r) {
    int i = tid + r * 256;
    int c = i >> 4, l = i & 15;
    float4 v = *(const float4*)(inp + (size_t)b * 262144 + (size_t)c * 1024 + hw0 + l * 4);
    t[(l * 4 + 0) * 257 + c] = v.x;
    t[(l * 4 + 1) * 257 + c] = v.y;
    t[(l * 4 + 2) * 257 + c] = v.z;
    t[(l * 4 + 3) * 257 + c] = v.w;
  }
  __syncthreads();
#pragma unroll
  for (int r = 0; r < 16; ++r) {
    int i = tid + r * 256;
    int hw = i >> 6, c4 = (i & 63) * 4;
    float4 o;
    o.x = t[hw * 257 + c4 + 0];
    o.y = t[hw * 257 + c4 + 1];
    o.z = t[hw * 257 + c4 + 2];
    o.w = t[hw * 257 + c4 + 3];
    *(float4*)(flat + ((size_t)(b * 1024 + hw0 + hw)) * 256 + c4) = o;
  }
}

// -------------------------------------------------------------- K3: argmin
// 512 WGs x 256 thr. WG = 128 points x all 1024 codes (4 chunks of 256).
// Double-buffered global_load_lds staging, ONE barrier per c-chunk; loads for
// chunk i+1 issue before computing chunk i. Staged values, FMA chain and
// epilogue are bitwise identical to the previously-passing version.
__global__ __launch_bounds__(256) void k_argmin(const float* __restrict__ inp,
                                                const float* __restrict__ embed,
                                                const float* __restrict__ esq,
                                                int* __restrict__ idx_out,
                                                float* __restrict__ idxf_out,
                                                int* __restrict__ cnt) {
  __shared__ float xs[2][8][128];  // [buf][cc][point]
  __shared__ float es[2][8][256];  // [buf][cc][code]
  __shared__ float xsqh[2][128];
  __shared__ float xsq_s[128];

  const int tid = threadIdx.x;
  const int lane = tid & 63;
  const int w = tid >> 6;          // wave id, uniform per wave
  const int n0 = blockIdx.x * 128;
  const int b = n0 >> 10;
  const int hw0 = n0 & 1023;
  const float* xbase = inp + (size_t)b * 262144 + hw0;  // x[p][c] = xbase[c*1024+p]

  // ---- xsq: replicate numpy pairwise sum over 256 (= pw(128) + pw(128))
  {
#pragma clang fp contract(off)
    const int p = tid & 127, h = tid >> 7;
    const float* xb = xbase + (size_t)(h * 128) * 1024 + p;
    float r[8];
#pragma unroll
    for (int j = 0; j < 8; ++j) { float v = xb[(size_t)j * 1024]; r[j] = v * v; }
#pragma unroll 1
    for (int blk = 1; blk < 16; ++blk) {
#pragma unroll
      for (int j = 0; j < 8; ++j) { float v = xb[(size_t)(blk * 8 + j) * 1024]; r[j] += v * v; }
    }
    xsqh[h][p] = ((r[0] + r[1]) + (r[2] + r[3])) + ((r[4] + r[5]) + (r[6] + r[7]));
    __syncthreads();
    if (tid < 128) xsq_s[tid] = xsqh[0][tid] + xsqh[1][tid];
    // visible after the prologue barrier below
  }

  const int tc = tid & 15, tr = tid >> 4;
  float bestv[8];
  int besti[8];
#pragma unroll
  for (int p = 0; p < 8; ++p) { bestv[p] = 3.0e38f; besti[p] = 0; }

// per-wave linear staging: lane i's 16B lands at ldsbase + i*16 (HW rule),
// which reproduces the old xs[cc][l*4]/es[cc][l*4] thread mapping exactly.
#define STAGE(buf, c0)                                                               \
  do {                                                                               \
    gll16(xbase + (size_t)((c0) + 2 * w + (lane >> 5)) * 1024 + (lane & 31) * 4,     \
          &xs[buf][0][0] + w * 256);                                                 \
    gll16(embed + (size_t)((c0) + w) * 1024 + k0 + lane * 4,                         \
          &es[buf][0][0] + w * 256);                                                 \
    gll16(embed + (size_t)((c0) + 4 + w) * 1024 + k0 + lane * 4,                     \
          &es[buf][0][0] + (4 + w) * 256);                                           \
  } while (0)

#pragma unroll 1
  for (int kt = 0; kt < 4; ++kt) {
    const int k0 = kt * 256;
    float acc[8][16];
#pragma unroll
    for (int p = 0; p < 8; ++p)
#pragma unroll
      for (int j = 0; j < 16; ++j) acc[p][j] = 0.f;

    STAGE(0, 0);
    __syncthreads();  // compiler drains vmcnt before s_barrier

#pragma unroll 1
    for (int cs = 0; cs < 32; ++cs) {
      const int cur = cs & 1;
      if (cs < 31) STAGE(cur ^ 1, (cs + 1) * 8);
#pragma unroll
      for (int cc = 0; cc < 8; ++cc) {
        alignas(16) float xr[8];
        alignas(16) float er[16];
        *(float4*)&xr[0] = *(float4*)&xs[cur][cc][tr * 8];
        *(float4*)&xr[4] = *(float4*)&xs[cur][cc][tr * 8 + 4];
#pragma unroll
        for (int g = 0; g < 4; ++g)
          *(float4*)&er[g * 4] = *(float4*)&es[cur][cc][g * 64 + tc * 4];
#pragma unroll
        for (int p = 0; p < 8; ++p)
#pragma unroll
          for (int j = 0; j < 16; ++j)
            acc[p][j] = __builtin_fmaf(xr[p], er[j], acc[p][j]);
      }
      __syncthreads();  // next-chunk loads landed; all waves done with buf cur
    }

    // epilogue: dist = (xsq - 2*dot) + esq, exact reference rounding order
    alignas(16) float esqr[16];
#pragma unroll
    for (int g = 0; g < 4; ++g)
      *(float4*)&esqr[g * 4] = *(const float4*)(esq + k0 + g * 64 + tc * 4);
#pragma unroll
    for (int p = 0; p < 8; ++p) {
      float xq = xsq_s[tr * 8 + p];
#pragma unroll
      for (int g = 0; g < 4; ++g)
#pragma unroll
        for (int jj = 0; jj < 4; ++jj) {
          int j = g * 4 + jj;
          float d = (xq - 2.0f * acc[p][j]) + esqr[j];
          int k = k0 + g * 64 + tc * 4 + jj;
          if (d < bestv[p]) { bestv[p] = d; besti[p] = k; }
        }
    }
  }
#undef STAGE

  // reduce (v, idx) lexicographically over the 16 tc lanes
#pragma unroll
  for (int p = 0; p < 8; ++p) {
    float v = bestv[p];
    int ii = besti[p];
#pragma unroll
    for (int off = 1; off < 16; off <<= 1) {
      float ov = __shfl_xor(v, off);
      int oi = __shfl_xor(ii, off);
      if (ov < v || (ov == v && oi < ii)) { v = ov; ii = oi; }
    }
    if (tc == 0) {
      int n = n0 + tr * 8 + p;
      idx_out[n] = ii;
      idxf_out[n] = (float)ii;
      atomicAdd(cnt + ii, 1);
    }
  }
}

// ---------------------------------------------------------------- K4: scan
// 1 block x 1024: exclusive prefix sum of cnt -> offs/cursor; also
// cluster_size_new and n (csn sum == 0.99*sum(cs) + 0.01*65536).
__global__ __launch_bounds__(1024) void k_scan(const int* __restrict__ cnt,
                                               const float* __restrict__ cs_in,
                                               int* __restrict__ offs,
                                               int* __restrict__ cursor,
                                               float* __restrict__ csn_out,
                                               float* __restrict__ nval) {
  __shared__ int sc[1024];
  __shared__ float red[1024];
  const int tid = threadIdx.x;
  const int c = cnt[tid];
  const float csv = cs_in[tid];
  sc[tid] = c;
  red[tid] = csv;
  __syncthreads();
#pragma unroll 1
  for (int off = 1; off < 1024; off <<= 1) {
    int v = sc[tid];
    int add = (tid >= off) ? sc[tid - off] : 0;
    __syncthreads();
    sc[tid] = v + add;
    __syncthreads();
  }
  const int incl = sc[tid];
  const int start = incl - c;
  offs[tid] = start;
  cursor[tid] = start;
  if (tid == 1023) offs[1024] = incl;
  csn_out[tid] = csv * 0.99f + (float)c * 0.01f;
#pragma unroll 1
  for (int off = 512; off > 0; off >>= 1) {
    if (tid < off) red[tid] += red[tid + off];
    __syncthreads();
  }
  if (tid == 0) nval[0] = 0.99f * red[0] + 0.01f * 65536.0f;
}

// ------------------------------------------------------------- K5: scatter
__global__ __launch_bounds__(256) void k_scatter(const int* __restrict__ idx,
                                                 int* __restrict__ cursor,
                                                 int* __restrict__ bucket) {
  const int n = blockIdx.x * 256 + threadIdx.x;
  const int k = idx[n];
  const int pos = atomicAdd(cursor + k, 1);
  bucket[pos] = n;
}

// -------------------------------------------------------------- K6: update
// One WG per code k: coalesced float4 row sums over the bucketed points.
__global__ __launch_bounds__(256) void k_update(const int* __restrict__ offs,
                                                const int* __restrict__ bucket,
                                                const float* __restrict__ flat,
                                                float* __restrict__ sums) {
  const int k = blockIdx.x;
  const int tid = threadIdx.x;
  const int w = tid >> 6, lane = tid & 63;
  __shared__ float sums_s[4][256];
  const int start = offs[k], end = offs[k + 1];
  float4 acc = make_float4(0.f, 0.f, 0.f, 0.f);
#pragma unroll 1
  for (int e = start + w; e < end; e += 4) {
    const float* row = flat + (size_t)bucket[e] * 256;
    float4 x4 = *(const float4*)(row + lane * 4);
    acc.x += x4.x; acc.y += x4.y; acc.z += x4.z; acc.w += x4.w;
  }
  *(float4*)&sums_s[w][lane * 4] = acc;
  __syncthreads();
  const float s = ((sums_s[0][tid] + sums_s[1][tid]) + sums_s[2][tid]) + sums_s[3][tid];
  sums[(size_t)k * 256 + tid] = s;
}

// ----------------------------------------------------------------- K7: ema
// 64x64 tiles: eavgn[c][k] = eavg[c][k]*.99 + sums[k][c]*.01; enew = eavgn/csk.
// All global accesses coalesced; sums transposed through LDS.
__global__ __launch_bounds__(256) void k_ema(const float* __restrict__ sums,
                                             const float* __restrict__ eavg,
                                             const float* __restrict__ csn,
                                             const float* __restrict__ nval,
                                             float* __restrict__ eavgn,
                                             float* __restrict__ enew) {
  __shared__ float t[64 * 65];
  __shared__ float csks[64];
  const int tid = threadIdx.x;
  const int k0 = (blockIdx.x >> 2) * 64, c0 = (blockIdx.x & 3) * 64;
  if (tid < 64) {
    float nv = nval[0];
    float cv = csn[k0 + tid];
    csks[tid] = (cv + 1e-5f) / (nv + 0.01024f) * nv;
  }
#pragma unroll
  for (int r = 0; r < 4; ++r) {
    int i = tid + r * 256;
    int kk = i >> 4, cL = (i & 15) * 4;
    float4 v = *(const float4*)(sums + (size_t)(k0 + kk) * 256 + c0 + cL);
    t[(cL + 0) * 65 + kk] = v.x;
    t[(cL + 1) * 65 + kk] = v.y;
    t[(cL + 2) * 65 + kk] = v.z;
    t[(cL + 3) * 65 + kk] = v.w;
  }
  __syncthreads();
#pragma unroll
  for (int r = 0; r < 4; ++r) {
    int i = tid + r * 256;
    int c = i >> 4, kL = (i & 15) * 4;
    size_t o = (size_t)(c0 + c) * 1024 + k0 + kL;
    float4 ev = *(const float4*)(eavg + o);
    float4 ean, en;
    ean.x = ev.x * 0.99f + t[c * 65 + kL + 0] * 0.01f;
    ean.y = ev.y * 0.99f + t[c * 65 + kL + 1] * 0.01f;
    ean.z = ev.z * 0.99f + t[c * 65 + kL + 2] * 0.01f;
    ean.w = ev.w * 0.99f + t[c * 65 + kL + 3] * 0.01f;
    en.x = ean.x / csks[kL + 0];
    en.y = ean.y / csks[kL + 1];
    en.z = ean.z / csks[kL + 2];
    en.w = ean.w / csks[kL + 3];
    *(float4*)(eavgn + o) = ean;
    *(float4*)(enew + o) = en;
  }
}

// --------------------------------------------------------------- K8: diffq
// diff = q - x (in place over flat), quantize = x + (q - x) bit-exactly,
// transposed back to (B,C,HW) via LDS.
__global__ __launch_bounds__(256) void k_diffq(const int* __restrict__ idx,
                                               const float* __restrict__ embedT,
                                               float* __restrict__ flat_diff,
                                               float* __restrict__ q_out) {
  const int tid = threadIdx.x;
  const int b = blockIdx.x >> 4;
  const int hw0 = (blockIdx.x & 15) * 64;
  const int n0 = b * 1024 + hw0;
  __shared__ float t[64 * 257];
#pragma unroll
  for (int r = 0; r < 16; ++r) {
    int i = tid + r * 256;
    int hw = i >> 6, c4 = (i & 63) * 4;
    int n = n0 + hw;
    int kk = idx[n];
    float4 q = *(const float4*)(embedT + (size_t)kk * 256 + c4);
    float4 x = *(const float4*)(flat_diff + (size_t)n * 256 + c4);
    float4 d;
    d.x = q.x - x.x; d.y = q.y - x.y; d.z = q.z - x.z; d.w = q.w - x.w;
    *(float4*)(flat_diff + (size_t)n * 256 + c4) = d;
    t[hw * 257 + c4 + 0] = x.x + d.x;
    t[hw * 257 + c4 + 1] = x.y + d.y;
    t[hw * 257 + c4 + 2] = x.z + d.z;
    t[hw * 257 + c4 + 3] = x.w + d.w;
  }
  __syncthreads();
#pragma unroll
  for (int r = 0; r < 16; ++r) {
    int i = tid + r * 256;
    int c = i >> 4, l = i & 15;
    float4 o;
    o.x = t[(l * 4 + 0) * 257 + c];
    o.y = t[(l * 4 + 1) * 257 + c];
    o.z = t[(l * 4 + 2) * 257 + c];
    o.w = t[(l * 4 + 3) * 257 + c];
    *(float4*)(q_out + (size_t)b * 262144 + (size_t)c * 1024 + hw0 + l * 4) = o;
  }
}

// ----------------------------------------------------------------- launch
extern "C" void kernel_launch(void* const* d_in, const int* in_sizes, int n_in,
                              void* d_out, int out_size, void* d_ws, size_t ws_size,
                              hipStream_t stream) {
  (void)in_sizes; (void)n_in; (void)out_size; (void)ws_size;
  const float* inp   = (const float*)d_in[0];
  const float* embed = (const float*)d_in[1];
  const float* cs_in = (const float*)d_in[2];
  const float* eavg  = (const float*)d_in[3];
  float* out = (float*)d_out;

  // workspace layout (float units)
  int*   idx_ws = (int*)d_ws;                    // 65536 ints
  int*   bucket = idx_ws + 65536;                // 65536 ints
  int*   cnt    = bucket + 65536;                // 1024 ints (zeroed by k_prep)
  int*   offs   = cnt + 1024;                    // 1025 ints
  int*   cursor = offs + 1536;                   // 1024 ints (padded start)
  float* wsf    = (float*)d_ws;
  float* nval   = wsf + 136192;                  // 1
  float* esq    = wsf + 136448;                  // 1024
  float* sums   = wsf + 137472;                  // 262144
  float* embedT = wsf + 399616;                  // 262144  (ends ~2.6 MB)

  float* flat = out + OUT_DIFF;

  hipLaunchKernelGGL(k_prep,    dim3(69),   dim3(256),  0, stream, embed, embedT, esq, cnt);
  hipLaunchKernelGGL(k_flatten, dim3(1024), dim3(256),  0, stream, inp, flat);
  hipLaunchKernelGGL(k_argmin,  dim3(512),  dim3(256),  0, stream, inp, embed, esq,
                     idx_ws, out + OUT_IDX, cnt);
  hipLaunchKernelGGL(k_scan,    dim3(1),    dim3(1024), 0, stream, cnt, cs_in, offs, cursor,
                     out + OUT_CSN, nval);
  hipLaunchKernelGGL(k_scatter, dim3(256),  dim3(256),  0, stream, idx_ws, cursor, bucket);
  hipLaunchKernelGGL(k_update,  dim3(1024), dim3(256),  0, stream, offs, bucket, flat, sums);
  hipLaunchKernelGGL(k_ema,     dim3(64),   dim3(256),  0, stream, sums, eavg, out + OUT_CSN,
                     nval, out + OUT_EAVG, out + OUT_ENEW);
  hipLaunchKernelGGL(k_diffq,   dim3(1024), dim3(256),  0, stream, idx_ws, embedT, flat, out);
}